// Round 11
// baseline (614.068 us; speedup 1.0000x reference)
//
#include <hip/hip_runtime.h>
#include <hip/hip_bf16.h>
#include <stdint.h>

// Problem constants (MultiScaleRetention: B=2, N=4096, D_MODEL=2048, H=4)
constexpr int Bb   = 2;
constexpr int Nn   = 4096;
constexpr int DM   = 2048;
constexpr int Hh   = 4;
constexpr int DK   = 256;    // KEY_DIM / H
constexpr int DV   = 512;    // D_MODEL / H
constexpr int QKS  = 2048;   // fused q|k row stride (q cols 0-1023, k cols 1024-2047)
constexpr int CH   = 64;     // chunk
constexpr int NC   = Nn / CH;   // 64 chunks
constexpr int M    = Bb * Nn;   // 8192 rows

typedef __attribute__((ext_vector_type(8))) short s16x8;   // 8 bf16 (4 VGPRs)
typedef __attribute__((ext_vector_type(4))) float f32x4;

__device__ __forceinline__ float b2f(uint16_t h) {
  return __uint_as_float(((uint32_t)h) << 16);
}
__device__ __forceinline__ uint16_t f2b(float f) {   // RNE, finite inputs
  uint32_t u = __float_as_uint(f);
  return (uint16_t)((u + 0x7fffu + ((u >> 16) & 1u)) >> 16);
}

// async global->LDS, 16B per lane; LDS dest = wave-uniform base + lane*16
__device__ __forceinline__ void gload16(const void* g, void* l) {
  __builtin_amdgcn_global_load_lds(
      (const __attribute__((address_space(1))) void*)g,
      (__attribute__((address_space(3))) void*)l, 16, 0, 0);
}

// ---------------------------------------------------------------------------
// fp32 -> bf16 bulk convert, 8 elems/thread
// ---------------------------------------------------------------------------
__global__ __launch_bounds__(256) void conv_f2b(const float* __restrict__ s,
                                                uint16_t* __restrict__ d, int n8) {
  int i = blockIdx.x * 256 + threadIdx.x;
  if (i >= n8) return;
  const float4* sp = (const float4*)s;
  float4 a = sp[2 * i], b = sp[2 * i + 1];
  uint4 o;
  o.x = (uint32_t)f2b(a.x) | ((uint32_t)f2b(a.y) << 16);
  o.y = (uint32_t)f2b(a.z) | ((uint32_t)f2b(a.w) << 16);
  o.z = (uint32_t)f2b(b.x) | ((uint32_t)f2b(b.y) << 16);
  o.w = (uint32_t)f2b(b.z) | ((uint32_t)f2b(b.w) << 16);
  ((uint4*)d)[i] = o;
}

// ---------------------------------------------------------------------------
// fused Wq/Wk/Wv/Wg fp32->bf16 into stacked [6144][2048] bf16. 8 elems/thread.
// ---------------------------------------------------------------------------
__global__ __launch_bounds__(256) void conv_w4(const float* __restrict__ Wq,
                                               const float* __restrict__ Wk,
                                               const float* __restrict__ Wv,
                                               const float* __restrict__ Wg,
                                               uint16_t* __restrict__ dst) {
  const int i = blockIdx.x * 256 + threadIdx.x;   // < 1572864
  const float* s; int off;
  if (i < 262144)       { s = Wq; off = i; }
  else if (i < 524288)  { s = Wk; off = i - 262144; }
  else if (i < 1048576) { s = Wv; off = i - 524288; }
  else                  { s = Wg; off = i - 1048576; }
  const float4* sp = (const float4*)s;
  float4 a = sp[2 * off], b = sp[2 * off + 1];
  uint4 o;
  o.x = (uint32_t)f2b(a.x) | ((uint32_t)f2b(a.y) << 16);
  o.y = (uint32_t)f2b(a.z) | ((uint32_t)f2b(a.w) << 16);
  o.z = (uint32_t)f2b(b.x) | ((uint32_t)f2b(b.y) << 16);
  o.w = (uint32_t)f2b(b.z) | ((uint32_t)f2b(b.w) << 16);
  ((uint4*)dst)[i] = o;
}

// ---------------------------------------------------------------------------
// Fused phase-1 GEMM: C = x[8192,2048] @ Wall[6144,2048]^T.
// Round-10 counted-vmcnt skeleton (3 buf, 2-deep prefetch, vmcnt(4), one
// barrier/K-tile, setprio) + NEW: T2 LDS XOR-swizzle (rule #21: linear
// gload dest + inverse-swizzled GLOBAL SOURCE + swizzled ds_read).
//   swizzle: logical (row, u16B) stored at phys unit u^(row&3).
//   staging: source col unit (l&3) -> (l&3)^((l>>2)&3)  [(l>>2)&3 == row&3]
//   reads:   fk -> fk ^ ((fr&3)<<3)  [row&3 == fr&3 for all frag rows]
// Kills the 8-way bank conflict on ds_read_b128 (lanes 0-15 at 64B row
// stride hit 2 banks) -> 4-way. Conflict counter 1.89e7 predicted ~halved.
// (512,2): round-8's (512,4) capped VGPR at 64 and spilled (10x regression).
// ---------------------------------------------------------------------------
__global__ __launch_bounds__(512, 2) void gemm_fused3(const uint16_t* __restrict__ A,
                                                      const uint16_t* __restrict__ W,
                                                      uint16_t* __restrict__ out0,
                                                      int K) {
  __shared__ uint16_t As[3][256 * 32];
  __shared__ uint16_t Bs[3][256 * 32];
  const int tid = threadIdx.x;
  const int l = tid & 63, w = tid >> 6;          // lane, wave 0..7
  const int wm = w >> 2, wn = w & 3;             // wave grid 2x4
  const int m0 = blockIdx.x * 256, n0 = blockIdx.y * 256;
  const int fr = l & 15, fk = (l >> 4) * 8;
  const int fkA = fk ^ ((fr & 3) << 3);          // swizzled read col
  const int sk = ((tid & 3) ^ ((tid >> 2) & 3)) * 8;  // pre-swizzled src col
  const uint16_t* aP = A + (size_t)(m0 + w * 16 + (l >> 2)) * K + sk;
  const uint16_t* wP = W + (size_t)(n0 + w * 16 + (l >> 2)) * K + sk;

  f32x4 acc[8][4];
#pragma unroll
  for (int mi = 0; mi < 8; ++mi)
#pragma unroll
    for (int nj = 0; nj < 4; ++nj) {
      f32x4 z = {0.f, 0.f, 0.f, 0.f};
      acc[mi][nj] = z;
    }

#define STAGE256(T, BUF)                                                     \
  {                                                                          \
    const size_t k0_ = (size_t)(T) * 32;                                     \
    uint16_t* as_ = &As[BUF][w * 512];                                       \
    uint16_t* bs_ = &Bs[BUF][w * 512];                                       \
    gload16(aP + k0_, as_);                                                  \
    gload16(aP + (size_t)128 * K + k0_, as_ + 4096);                         \
    gload16(wP + k0_, bs_);                                                  \
    gload16(wP + (size_t)128 * K + k0_, bs_ + 4096);                         \
  }

  const int NT = K / 32;
  STAGE256(0, 0);                                 // 4 loads in flight
  STAGE256(1, 1);                                 // 8 in flight
  for (int t = 0; t < NT; ++t) {
    // wait own tile-t loads (leave tile t+1's 4 in flight), publish via barrier
    if (t < NT - 1) asm volatile("s_waitcnt vmcnt(4)" ::: "memory");
    else            asm volatile("s_waitcnt vmcnt(0)" ::: "memory");
    __builtin_amdgcn_s_barrier();
    __builtin_amdgcn_sched_barrier(0);            // pin: nothing hoists above
    if (t + 2 < NT) STAGE256(t + 2, (t + 2) % 3); // buf[(t-1)%3]: free by barrier
    const int cur = t % 3;
    s16x8 af[8], bf4[4];
    const uint16_t* Ab = &As[cur][(wm * 128 + fr) * 32 + fkA];
    const uint16_t* Bp = &Bs[cur][(wn * 64 + fr) * 32 + fkA];
#pragma unroll
    for (int mi = 0; mi < 8; ++mi) af[mi] = *(const s16x8*)(Ab + mi * 512);
#pragma unroll
    for (int nj = 0; nj < 4; ++nj) bf4[nj] = *(const s16x8*)(Bp + nj * 512);
    __builtin_amdgcn_s_setprio(1);
#pragma unroll
    for (int mi = 0; mi < 8; ++mi)
#pragma unroll
      for (int nj = 0; nj < 4; ++nj)
        acc[mi][nj] = __builtin_amdgcn_mfma_f32_16x16x32_bf16(af[mi], bf4[nj],
                                                              acc[mi][nj], 0, 0, 0);
    __builtin_amdgcn_s_setprio(0);
  }
#undef STAGE256

  // block-uniform output region select (regions 32MB = 16777216 uint16 apart)
  uint16_t* Cb = out0 + (size_t)(n0 >> 11) * 16777216;
  const int r0 = m0 + wm * 128 + (l >> 4) * 4;
  const int c0 = (n0 & 2047) + wn * 64 + fr;
#pragma unroll
  for (int mi = 0; mi < 8; ++mi)
#pragma unroll
    for (int nj = 0; nj < 4; ++nj)
#pragma unroll
      for (int p = 0; p < 4; ++p) {
        const int row = r0 + mi * 16 + p;
        const int col = c0 + nj * 16;
        Cb[(size_t)row * 2048 + col] = f2b(acc[mi][nj][p]);
      }
}

// ---------------------------------------------------------------------------
// Final GEMM: C[M,N]fp32 = A @ W^T, 256x128 tile, same skeleton + T2 swizzle.
// ---------------------------------------------------------------------------
__global__ __launch_bounds__(512, 2) void gemm_fin(const uint16_t* __restrict__ A,
                                                   const uint16_t* __restrict__ W,
                                                   float* __restrict__ C,
                                                   int Nd, int K) {
  __shared__ uint16_t As[3][256 * 32];
  __shared__ uint16_t Bs[3][128 * 32];
  const int tid = threadIdx.x;
  const int l = tid & 63, w = tid >> 6;
  const int wm = w >> 2, wn = w & 3;
  const int m0 = blockIdx.x * 256, n0 = blockIdx.y * 128;
  const int fr = l & 15, fk = (l >> 4) * 8;
  const int fkA = fk ^ ((fr & 3) << 3);          // swizzled read col
  const int sk = ((tid & 3) ^ ((tid >> 2) & 3)) * 8;  // pre-swizzled src col
  const uint16_t* aP = A + (size_t)(m0 + w * 16 + (l >> 2)) * K + sk;
  const uint16_t* wP = W + (size_t)(n0 + w * 16 + (l >> 2)) * K + sk;

  f32x4 acc[8][2];
#pragma unroll
  for (int mi = 0; mi < 8; ++mi)
#pragma unroll
    for (int nj = 0; nj < 2; ++nj) {
      f32x4 z = {0.f, 0.f, 0.f, 0.f};
      acc[mi][nj] = z;
    }

#define STAGEF(T, BUF)                                                       \
  {                                                                          \
    const size_t k0_ = (size_t)(T) * 32;                                     \
    uint16_t* as_ = &As[BUF][w * 512];                                       \
    gload16(aP + k0_, as_);                                                  \
    gload16(aP + (size_t)128 * K + k0_, as_ + 4096);                         \
    gload16(wP + k0_, &Bs[BUF][w * 512]);                                    \
  }

  const int NT = K / 32;
  STAGEF(0, 0);
  STAGEF(1, 1);
  for (int t = 0; t < NT; ++t) {
    if (t < NT - 1) asm volatile("s_waitcnt vmcnt(3)" ::: "memory");
    else            asm volatile("s_waitcnt vmcnt(0)" ::: "memory");
    __builtin_amdgcn_s_barrier();
    __builtin_amdgcn_sched_barrier(0);
    if (t + 2 < NT) STAGEF(t + 2, (t + 2) % 3);
    const int cur = t % 3;
    s16x8 af[8], bf2[2];
    const uint16_t* Ab = &As[cur][(wm * 128 + fr) * 32 + fkA];
    const uint16_t* Bp = &Bs[cur][(wn * 32 + fr) * 32 + fkA];
#pragma unroll
    for (int mi = 0; mi < 8; ++mi) af[mi] = *(const s16x8*)(Ab + mi * 512);
#pragma unroll
    for (int nj = 0; nj < 2; ++nj) bf2[nj] = *(const s16x8*)(Bp + nj * 512);
    __builtin_amdgcn_s_setprio(1);
#pragma unroll
    for (int mi = 0; mi < 8; ++mi)
#pragma unroll
      for (int nj = 0; nj < 2; ++nj)
        acc[mi][nj] = __builtin_amdgcn_mfma_f32_16x16x32_bf16(af[mi], bf2[nj],
                                                              acc[mi][nj], 0, 0, 0);
    __builtin_amdgcn_s_setprio(0);
  }
#undef STAGEF

  const int r0 = m0 + wm * 128 + (l >> 4) * 4;
  const int c0 = n0 + wn * 32 + fr;
#pragma unroll
  for (int mi = 0; mi < 8; ++mi)
#pragma unroll
    for (int nj = 0; nj < 2; ++nj)
#pragma unroll
      for (int p = 0; p < 4; ++p)
        C[(size_t)(r0 + mi * 16 + p) * Nd + c0 + nj * 16] = acc[mi][nj][p];
}

// ---------------------------------------------------------------------------
// RoPE on fused bf16 qk rows (stride QKS) in place; q scaled by 1/16.
// ---------------------------------------------------------------------------
__global__ void rope_kernel(uint16_t* __restrict__ qk) {
  const int idx = blockIdx.x * 256 + threadIdx.x;   // < B*N*H*128
  const int i = idx & 127;
  const int h = (idx >> 7) & 3;
  const int n = (idx >> 9) & (Nn - 1);
  const int b = idx >> 21;
  const size_t base = ((size_t)(b * Nn + n)) * QKS + h * DK;
  const float invf = (float)exp((double)i * -0.071955784156063938);  // 1e4^(-i/128)
  const float theta = (float)n * invf;
  float sn, cs;
  sincosf(theta, &sn, &cs);
  float x1 = b2f(qk[base + i]), x2 = b2f(qk[base + 128 + i]);
  qk[base + i]       = f2b((x1 * cs - x2 * sn) * 0.0625f);
  qk[base + 128 + i] = f2b((x2 * cs + x1 * sn) * 0.0625f);
  x1 = b2f(qk[base + 1024 + i]); x2 = b2f(qk[base + 1024 + 128 + i]);
  qk[base + 1024 + i]       = f2b(x1 * cs - x2 * sn);
  qk[base + 1024 + 128 + i] = f2b(x2 * cs + x1 * sn);
}

// ---------------------------------------------------------------------------
// v transpose: vt[bh][w][n] = v[b][n][h*DV + w].  64x64 LDS tiles.
// ---------------------------------------------------------------------------
__global__ __launch_bounds__(256) void transpose_v(const uint16_t* __restrict__ v,
                                                   uint16_t* __restrict__ vt) {
  const int nt = blockIdx.x & 63;
  const int wt = (blockIdx.x >> 6) & 7;
  const int bh = blockIdx.x >> 9;
  const int b = bh >> 2, h = bh & 3;
  __shared__ uint16_t t[64][72];
  const int lr = threadIdx.x >> 2, lc = (threadIdx.x & 3) * 16;
  const uint16_t* src = v + ((size_t)(b * Nn + nt * 64 + lr)) * DM + h * DV + wt * 64 + lc;
  *(uint4*)&t[lr][lc]     = *(const uint4*)src;
  *(uint4*)&t[lr][lc + 8] = *(const uint4*)(src + 8);
  __syncthreads();
  uint16_t out[16];
#pragma unroll
  for (int e = 0; e < 16; ++e) out[e] = t[lc + e][lr];
  uint16_t* dst = vt + ((size_t)bh * 512 + wt * 64 + lr) * 4096 + nt * 64 + lc;
  *(uint4*)dst       = *(uint4*)&out[0];
  *(uint4*)(dst + 8) = *(uint4*)&out[8];
}

// ---------------------------------------------------------------------------
// k transpose + gamma-scale: kt[bh][d][n] = gamma_h^(63-(n&63)) * k[b][n][d]
// ---------------------------------------------------------------------------
__global__ __launch_bounds__(256) void transpose_k(const uint16_t* __restrict__ qk,
                                                   uint16_t* __restrict__ kt) {
  const int nt = blockIdx.x & 63;
  const int dt = (blockIdx.x >> 6) & 3;
  const int bh = blockIdx.x >> 8;
  const int b = bh >> 2, h = bh & 3;
  __shared__ uint16_t t[64][72];
  const int lr = threadIdx.x >> 2, lc = (threadIdx.x & 3) * 16;
  const uint16_t* src = qk + ((size_t)(b * Nn + nt * 64 + lr)) * QKS + 1024 + h * DK + dt * 64 + lc;
  *(uint4*)&t[lr][lc]     = *(const uint4*)src;
  *(uint4*)&t[lr][lc + 8] = *(const uint4*)(src + 8);
  __syncthreads();
  const float l2g = log2f(1.f - exp2f(-5.f - (float)h));
  uint16_t out[16];
#pragma unroll
  for (int e = 0; e < 16; ++e)
    out[e] = f2b(b2f(t[lc + e][lr]) * exp2f((float)(63 - (lc + e)) * l2g));
  uint16_t* dst = kt + ((size_t)bh * 256 + dt * 64 + lr) * 4096 + nt * 64 + lc;
  *(uint4*)dst       = *(uint4*)&out[0];
  *(uint4*)(dst + 8) = *(uint4*)&out[8];
}

// ---------------------------------------------------------------------------
// Intra-chunk attention via MFMA: attn[bh][c][i][j] (bf16).
// ---------------------------------------------------------------------------
__global__ __launch_bounds__(256) void attn_mfma(const uint16_t* __restrict__ qk,
                                                 uint16_t* __restrict__ attn) {
  const int c  = blockIdx.x & 63;
  const int bh = blockIdx.x >> 6;
  const int b = bh >> 2, h = bh & 3;
  const int tid = threadIdx.x;
  const int l = tid & 63, w = tid >> 6;
  const int fr = l & 15, fk = (l >> 4) * 8;
  const int n0 = c * CH;
  const uint16_t* qbase = qk + ((size_t)(b * Nn + n0)) * QKS + h * DK;
  const uint16_t* kbase = qbase + 1024;
  f32x4 acc[4];
#pragma unroll
  for (int nj = 0; nj < 4; ++nj) {
    f32x4 z = {0.f, 0.f, 0.f, 0.f};
    acc[nj] = z;
  }
#pragma unroll
  for (int ks = 0; ks < 8; ++ks) {
    s16x8 qf = *(const s16x8*)(qbase + (size_t)(w * 16 + fr) * QKS + ks * 32 + fk);
    s16x8 kf[4];
#pragma unroll
    for (int nj = 0; nj < 4; ++nj)
      kf[nj] = *(const s16x8*)(kbase + (size_t)(nj * 16 + fr) * QKS + ks * 32 + fk);
#pragma unroll
    for (int nj = 0; nj < 4; ++nj)
      acc[nj] = __builtin_amdgcn_mfma_f32_16x16x32_bf16(qf, kf[nj], acc[nj], 0, 0, 0);
  }
  const float l2g = log2f(1.f - exp2f(-5.f - (float)h));
  uint16_t* ab = attn + ((size_t)bh * 64 + c) * 4096;
  const int rbase = (l >> 4) * 4;
#pragma unroll
  for (int pp = 0; pp < 4; ++pp) {
    const int i = w * 16 + rbase + pp;
#pragma unroll
    for (int nj = 0; nj < 4; ++nj) {
      const int j = nj * 16 + fr;
      const float val = (i >= j) ? acc[nj][pp] * exp2f((float)(i - j) * l2g) : 0.f;
      ab[(size_t)i * 64 + j] = f2b(val);
    }
  }
}

// ---------------------------------------------------------------------------
// Kernel A: U_c^T[w,d] = sum_j vt[w,j] * kt[d,j]  (direct-global fragments)
// ---------------------------------------------------------------------------
__global__ __launch_bounds__(256) void chunk_outer(const uint16_t* __restrict__ kt,
                                                   const uint16_t* __restrict__ vt,
                                                   uint16_t* __restrict__ U, int p) {
  const int c  = blockIdx.x & 63;
  const int bh = blockIdx.x >> 6;
  const int tid = threadIdx.x;
  const int l = tid & 63, w = tid >> 6;
  const int wrow = (w >> 1) * 64;     // w' base (M)
  const int wcol = (w & 1) * 128;     // d  base (N)
  const int fr = l & 15, fk = (l >> 4) * 8;
  const int n0 = c * CH;
  const uint16_t* vtb = vt + ((size_t)bh * 512 + p * 128) * 4096 + n0;
  const uint16_t* ktb = kt + ((size_t)bh * 256) * 4096 + n0;
  f32x4 acc[4][8];
#pragma unroll
  for (int mi = 0; mi < 4; ++mi)
#pragma unroll
    for (int nj = 0; nj < 8; ++nj) {
      f32x4 z = {0.f, 0.f, 0.f, 0.f};
      acc[mi][nj] = z;
    }
#pragma unroll
  for (int ks = 0; ks < 2; ++ks) {
    s16x8 af[4], bf8[8];
#pragma unroll
    for (int mi = 0; mi < 4; ++mi)
      af[mi] = *(const s16x8*)(vtb + (size_t)(wrow + mi * 16 + fr) * 4096 + ks * 32 + fk);
#pragma unroll
    for (int nj = 0; nj < 8; ++nj)
      bf8[nj] = *(const s16x8*)(ktb + (size_t)(wcol + nj * 16 + fr) * 4096 + ks * 32 + fk);
#pragma unroll
    for (int mi = 0; mi < 4; ++mi)
#pragma unroll
      for (int nj = 0; nj < 8; ++nj)
        acc[mi][nj] = __builtin_amdgcn_mfma_f32_16x16x32_bf16(af[mi], bf8[nj],
                                                              acc[mi][nj], 0, 0, 0);
  }
  uint16_t* Ub = U + (size_t)bh * 2097152 + (size_t)c * 32768;
  const int rbase = (l >> 4) * 4;
#pragma unroll
  for (int mi = 0; mi < 4; ++mi)
#pragma unroll
    for (int nj = 0; nj < 8; ++nj)
#pragma unroll
      for (int pp = 0; pp < 4; ++pp) {
        const int wq = wrow + mi * 16 + rbase + pp;
        const int d  = wcol + nj * 16 + fr;
        Ub[(size_t)wq * 256 + d] = f2b(acc[mi][nj][pp]);
      }
}

// ---------------------------------------------------------------------------
// Kernel B: in-place state scan (slot c -> S_c), 8-batch load prefetch.
// ---------------------------------------------------------------------------
__global__ __launch_bounds__(256) void state_scan(uint16_t* __restrict__ U) {
  const int gid = blockIdx.x * 256 + threadIdx.x;   // < 8*32768 = 262144
  const int bh = gid >> 15;
  const int e  = gid & 32767;
  const int h  = bh & 3;
  const float l2g = log2f(1.f - exp2f(-5.f - (float)h));
  const float gC = exp2f(64.f * l2g);
  uint16_t* p = U + (size_t)bh * 2097152 + e;
  float S = 0.f;
  for (int cb = 0; cb < 8; ++cb) {
    uint16_t* base = p + (size_t)cb * 8 * 32768;
    float u[8];
#pragma unroll
    for (int ee = 0; ee < 8; ++ee) u[ee] = b2f(base[(size_t)ee * 32768]);
#pragma unroll
    for (int ee = 0; ee < 8; ++ee) {
      base[(size_t)ee * 32768] = f2b(S);
      S = gC * S + u[ee];
    }
  }
}

// ---------------------------------------------------------------------------
// Kernel C: o[i,w] = (attn_c @ v_c)[i,w] + gamma^(i+1)*(q_c @ S_c)[i,w]
// ---------------------------------------------------------------------------
__global__ __launch_bounds__(256) void scan_out(const uint16_t* __restrict__ qk,
                                                const uint16_t* __restrict__ vt,
                                                const uint16_t* __restrict__ attn,
                                                const uint16_t* __restrict__ U,
                                                uint16_t* __restrict__ o, int p) {
  const int c  = blockIdx.x & 63;
  const int bh = blockIdx.x >> 6;
  const int b = bh >> 2, h = bh & 3;
  const int tid = threadIdx.x;
  const int l = tid & 63, wv = tid >> 6;
  const int wcol = wv * 32;                 // output col base (within pass 128)
  const int fr = l & 15, fk = (l >> 4) * 8;
  const int n0 = c * CH;
  f32x4 aQS[4][2], aPV[4][2];
#pragma unroll
  for (int mi = 0; mi < 4; ++mi)
#pragma unroll
    for (int nj = 0; nj < 2; ++nj) {
      f32x4 z = {0.f, 0.f, 0.f, 0.f};
      aQS[mi][nj] = z; aPV[mi][nj] = z;
    }
  const uint16_t* qbase = qk + ((size_t)(b * Nn + n0)) * QKS + h * DK;
  const uint16_t* Ub = U + (size_t)bh * 2097152 + (size_t)c * 32768;
  // q @ S  (K = 256)
#pragma unroll
  for (int ks = 0; ks < 8; ++ks) {
    s16x8 qf[4], sf[2];
#pragma unroll
    for (int mi = 0; mi < 4; ++mi)
      qf[mi] = *(const s16x8*)(qbase + (size_t)(mi * 16 + fr) * QKS + ks * 32 + fk);
#pragma unroll
    for (int nj = 0; nj < 2; ++nj)
      sf[nj] = *(const s16x8*)(Ub + (size_t)(wcol + nj * 16 + fr) * 256 + ks * 32 + fk);
#pragma unroll
    for (int mi = 0; mi < 4; ++mi)
#pragma unroll
      for (int nj = 0; nj < 2; ++nj)
        aQS[mi][nj] = __builtin_amdgcn_mfma_f32_16x16x32_bf16(qf[mi], sf[nj],
                                                              aQS[mi][nj], 0, 0, 0);
  }
  // attn @ v  (K = 64)
  const uint16_t* ab = attn + ((size_t)bh * 64 + c) * 4096;
  const uint16_t* vtb = vt + ((size_t)bh * 512 + p * 128) * 4096 + n0;
#pragma unroll
  for (int ks = 0; ks < 2; ++ks) {
    s16x8 af[4], vf[2];
#pragma unroll
    for (int mi = 0; mi < 4; ++mi)
      af[mi] = *(const s16x8*)(ab + (size_t)(mi * 16 + fr) * 64 + ks * 32 + fk);
#pragma unroll
    for (int nj = 0; nj < 2; ++nj)
      vf[nj] = *(const s16x8*)(vtb + (size_t)(wcol + nj * 16 + fr) * 4096 + ks * 32 + fk);
#pragma unroll
    for (int mi = 0; mi < 4; ++mi)
#pragma unroll
      for (int nj = 0; nj < 2; ++nj)
        aPV[mi][nj] = __builtin_amdgcn_mfma_f32_16x16x32_bf16(af[mi], vf[nj],
                                                              aPV[mi][nj], 0, 0, 0);
  }
  const float l2g = log2f(1.f - exp2f(-5.f - (float)h));
  const int rbase = (l >> 4) * 4;
#pragma unroll
  for (int mi = 0; mi < 4; ++mi)
#pragma unroll
    for (int pp = 0; pp < 4; ++pp) {
      const int i = mi * 16 + rbase + pp;
      const float gi = exp2f((float)(i + 1) * l2g);
#pragma unroll
      for (int nj = 0; nj < 2; ++nj) {
        const int wc_ = wcol + nj * 16 + fr;
        const float val = aPV[mi][nj][pp] + gi * aQS[mi][nj][pp];
        o[((size_t)(b * Nn + n0 + i)) * DM + h * DV + p * 128 + wc_] = f2b(val);
      }
    }
}

// ---------------------------------------------------------------------------
// GroupNorm over DV per (b,n,h) + SiLU gate (o bf16), in place into g.
// ---------------------------------------------------------------------------
__global__ __launch_bounds__(256) void gn_gate(const uint16_t* __restrict__ o,
                                               uint16_t* __restrict__ g,
                                               const float* __restrict__ gw) {
  const int bn = blockIdx.x;
  const int tid = threadIdx.x;
  const int h = tid >> 6;
  const int lane = tid & 63;
  const size_t base = (size_t)bn * DM + h * DV + lane * 8;
  uint4 ov4 = *(const uint4*)&o[base];
  float ov[8] = { b2f((uint16_t)ov4.x), b2f((uint16_t)(ov4.x >> 16)),
                  b2f((uint16_t)ov4.y), b2f((uint16_t)(ov4.y >> 16)),
                  b2f((uint16_t)ov4.z), b2f((uint16_t)(ov4.z >> 16)),
                  b2f((uint16_t)ov4.w), b2f((uint16_t)(ov4.w >> 16)) };
  float ss = 0.f;
#pragma unroll
  for (int e = 0; e < 8; ++e) ss += ov[e] * ov[e];
#pragma unroll
  for (int m = 1; m < 64; m <<= 1) ss += __shfl_xor(ss, m, 64);
  const float r = rsqrtf(ss * (1.f / 512.f) + 1e-5f);
  uint4 gv = *(const uint4*)&g[base];
  float gf[8] = { b2f((uint16_t)gv.x), b2f((uint16_t)(gv.x >> 16)),
                  b2f((uint16_t)gv.y), b2f((uint16_t)(gv.y >> 16)),
                  b2f((uint16_t)gv.z), b2f((uint16_t)(gv.z >> 16)),
                  b2f((uint16_t)gv.w), b2f((uint16_t)(gv.w >> 16)) };
  const float* gwp = gw + lane * 8;
  uint16_t res[8];
#pragma unroll
  for (int e = 0; e < 8; ++e) {
    float sil = gf[e] / (1.f + expf(-gf[e]));
    res[e] = f2b(ov[e] * r * gwp[e] * sil);
  }
  uint4 outv;
  outv.x = (uint32_t)res[0] | ((uint32_t)res[1] << 16);
  outv.y = (uint32_t)res[2] | ((uint32_t)res[3] << 16);
  outv.z = (uint32_t)res[4] | ((uint32_t)res[5] << 16);
  outv.w = (uint32_t)res[6] | ((uint32_t)res[7] << 16);
  *(uint4*)&g[base] = outv;
}

// ---------------------------------------------------------------------------
// ws layout (MB), peak 160 (proven size). Overlays, write-before-read ordered:
//   [  0, 32)  xb (dead after fused GEMM)            -> U (scan)
//   [ 32, 64)  qkb   [ 64, 96) vb -> kt[64,80) attn[80,84) wob[84,92)
//   [ 96,128)  gb
//   [128,152)  wall (stacked Wq;Wk;Wv;Wg, dead after fused GEMM)
//                                                    -> vt[128,160)
// o16 (bf16) lives in d_out's first 32MB until gn_gate; final GEMM overwrites
// d_out fp32. Every region fully written before read -> graph-replay safe.
// ---------------------------------------------------------------------------
extern "C" void kernel_launch(void* const* d_in, const int* in_sizes, int n_in,
                              void* d_out, int out_size, void* d_ws, size_t ws_size,
                              hipStream_t stream) {
  const float* x  = (const float*)d_in[0];
  const float* Wq = (const float*)d_in[1];
  const float* Wk = (const float*)d_in[2];
  const float* Wv = (const float*)d_in[3];
  const float* Wg = (const float*)d_in[4];
  const float* Wo = (const float*)d_in[5];
  const float* gw = (const float*)d_in[6];

  char* base = (char*)d_ws;
  uint16_t* xb   = (uint16_t*)(base);                       // [0,32)
  uint16_t* U    = (uint16_t*)(base);                       // overlays xb (scan)
  uint16_t* qkb  = (uint16_t*)(base + ((size_t)32 << 20));  // [32,64)
  uint16_t* vb   = (uint16_t*)(base + ((size_t)64 << 20));  // [64,96)
  uint16_t* kt   = (uint16_t*)(base + ((size_t)64 << 20));  // overlays vb
  uint16_t* attn = (uint16_t*)(base + ((size_t)80 << 20));  // overlays vb
  uint16_t* wob  = (uint16_t*)(base + ((size_t)84 << 20));  // overlays vb
  uint16_t* gb   = (uint16_t*)(base + ((size_t)96 << 20));  // [96,128)
  uint16_t* wall = (uint16_t*)(base + ((size_t)128 << 20)); // [128,152)
  uint16_t* vt   = (uint16_t*)(base + ((size_t)128 << 20)); // overlays wall
  uint16_t* qb   = qkb;                    // q = cols 0-1023
  uint16_t* o16  = (uint16_t*)d_out;       // bf16 o scratch (first 32MB)

  dim3 blk(256), blkG(512);
  // phase 1: conversions + ONE fused GEMM (qk|v|g), 768 blocks
  conv_f2b<<<dim3(8192), blk, 0, stream>>>(x, xb, M * DM / 8);
  conv_w4<<<dim3(6144), blk, 0, stream>>>(Wq, Wk, Wv, Wg, wall);
  gemm_fused3<<<dim3(M/256, 6144/256), blkG, 0, stream>>>(xb, wall, qkb, DM);
  // phase 2: rope; transposes (vb, wall die); attn
  rope_kernel<<<dim3((Bb*Nn*Hh*128)/256), blk, 0, stream>>>(qkb);
  transpose_v<<<dim3(8*8*64), blk, 0, stream>>>(vb, vt);     // vb -> dead
  conv_f2b<<<dim3(2048), blk, 0, stream>>>(Wo, wob, DM * DM / 8);
  transpose_k<<<dim3(8*4*64), blk, 0, stream>>>(qkb, kt);
  attn_mfma<<<dim3(Bb*Hh*NC), blk, 0, stream>>>(qkb, attn);
  // scan: 4 passes of 128 dv cols; U overlays dead xb
  for (int p = 0; p < 4; ++p) {
    chunk_outer<<<dim3(Bb*Hh*NC),  blk, 0, stream>>>(kt, vt, U, p);
    state_scan<<<dim3(1024),       blk, 0, stream>>>(U);
    scan_out<<<dim3(Bb*Hh*NC),     blk, 0, stream>>>(qb, vt, attn, U, o16, p);
  }
  // epilogue
  gn_gate<<<dim3(M), blk, 0, stream>>>(o16, gb, gw);
  gemm_fin<<<dim3(M/256, DM/128), blkG, 0, stream>>>(gb, wob, (float*)d_out, DM, DM);
}

// Round 12
// 548.986 us; speedup vs baseline: 1.1185x; 1.1185x over previous
//
#include <hip/hip_runtime.h>
#include <hip/hip_bf16.h>
#include <stdint.h>

// Problem constants (MultiScaleRetention: B=2, N=4096, D_MODEL=2048, H=4)
constexpr int Bb   = 2;
constexpr int Nn   = 4096;
constexpr int DM   = 2048;
constexpr int Hh   = 4;
constexpr int DK   = 256;    // KEY_DIM / H
constexpr int DV   = 512;    // D_MODEL / H
constexpr int QKS  = 2048;   // fused q|k row stride (q cols 0-1023, k cols 1024-2047)
constexpr int CH   = 64;     // chunk
constexpr int NC   = Nn / CH;   // 64 chunks
constexpr int M    = Bb * Nn;   // 8192 rows

typedef __attribute__((ext_vector_type(8))) short s16x8;   // 8 bf16 (4 VGPRs)
typedef __attribute__((ext_vector_type(4))) float f32x4;

__device__ __forceinline__ float b2f(uint16_t h) {
  return __uint_as_float(((uint32_t)h) << 16);
}
__device__ __forceinline__ uint16_t f2b(float f) {   // RNE, finite inputs
  uint32_t u = __float_as_uint(f);
  return (uint16_t)((u + 0x7fffu + ((u >> 16) & 1u)) >> 16);
}

// async global->LDS, 16B per lane; LDS dest = wave-uniform base + lane*16
__device__ __forceinline__ void gload16(const void* g, void* l) {
  __builtin_amdgcn_global_load_lds(
      (const __attribute__((address_space(1))) void*)g,
      (__attribute__((address_space(3))) void*)l, 16, 0, 0);
}

#define BARRIER()  asm volatile("s_barrier" ::: "memory")
#define WAITLGKM() do { asm volatile("s_waitcnt lgkmcnt(0)" ::: "memory"); \
                        __builtin_amdgcn_sched_barrier(0); } while (0)
#define VMCNT4()   asm volatile("s_waitcnt vmcnt(4)" ::: "memory")
#define VMCNT0()   asm volatile("s_waitcnt vmcnt(0)" ::: "memory")

// ---------------------------------------------------------------------------
// fp32 -> bf16 bulk convert, 8 elems/thread
// ---------------------------------------------------------------------------
__global__ __launch_bounds__(256) void conv_f2b(const float* __restrict__ s,
                                                uint16_t* __restrict__ d, int n8) {
  int i = blockIdx.x * 256 + threadIdx.x;
  if (i >= n8) return;
  const float4* sp = (const float4*)s;
  float4 a = sp[2 * i], b = sp[2 * i + 1];
  uint4 o;
  o.x = (uint32_t)f2b(a.x) | ((uint32_t)f2b(a.y) << 16);
  o.y = (uint32_t)f2b(a.z) | ((uint32_t)f2b(a.w) << 16);
  o.z = (uint32_t)f2b(b.x) | ((uint32_t)f2b(b.y) << 16);
  o.w = (uint32_t)f2b(b.z) | ((uint32_t)f2b(b.w) << 16);
  ((uint4*)d)[i] = o;
}

// ---------------------------------------------------------------------------
// fused Wq/Wk/Wv/Wg fp32->bf16 into stacked [6144][2048] bf16. 8 elems/thread.
// ---------------------------------------------------------------------------
__global__ __launch_bounds__(256) void conv_w4(const float* __restrict__ Wq,
                                               const float* __restrict__ Wk,
                                               const float* __restrict__ Wv,
                                               const float* __restrict__ Wg,
                                               uint16_t* __restrict__ dst) {
  const int i = blockIdx.x * 256 + threadIdx.x;   // < 1572864
  const float* s; int off;
  if (i < 262144)       { s = Wq; off = i; }
  else if (i < 524288)  { s = Wk; off = i - 262144; }
  else if (i < 1048576) { s = Wv; off = i - 524288; }
  else                  { s = Wg; off = i - 1048576; }
  const float4* sp = (const float4*)s;
  float4 a = sp[2 * off], b = sp[2 * off + 1];
  uint4 o;
  o.x = (uint32_t)f2b(a.x) | ((uint32_t)f2b(a.y) << 16);
  o.y = (uint32_t)f2b(a.z) | ((uint32_t)f2b(a.w) << 16);
  o.z = (uint32_t)f2b(b.x) | ((uint32_t)f2b(b.y) << 16);
  o.w = (uint32_t)f2b(b.z) | ((uint32_t)f2b(b.w) << 16);
  ((uint4*)dst)[i] = o;
}

// ---------------------------------------------------------------------------
// Fused phase-1 GEMM, 8-PHASE template (m201-class schedule, derived fresh):
//   C = x[8192,2048] @ Wall[6144,2048]^T, BM=BN=256, 512 thr = 8 waves (2x4),
//   wave tile 128x64 (8mi x 4nj frags of 16x16x32).
// LDS 128 KB: [slot(2)][khalf(2)][256 rows][32 cols] per matrix (64B rows).
// Iteration = 2 K-tiles (BK=64 each, as 2 K-halves of 32): 8 phases, each =
//   {ds_read (10 or 2), stage 1 half (2 gload16), barrier, lgkmcnt(0)+
//    sched_barrier, setprio(1), 16 MFMA (8mi x 2nj x 1kh), setprio(0),
//    [vmcnt(4) at ph4/ph8], barrier}.
// Read phases: ph1/2: slot0-kh0 (nj01/nj23), ph3/4: slot0-kh1,
//              ph5/6: slot1-kh0, ph7/8: slot1-kh1.
// Stationary staging (target dead >=1 barrier before issue; landing covered
// by vmcnt(4)+barrier checkpoints at ph4/ph8 -> 2 halves always in flight):
//   ph1: A slot1-kh1 (tile 2i+1)   [prev reader: ph7/8 of prev iter]
//   ph2: B slot1-kh1 (tile 2i+1)
//   ph3: A slot0-kh0 (tile 2i+2)   [dead after ph2]
//   ph4: B slot0-kh0 (tile 2i+2) + vmcnt(4)  [guarantees ph1,2 landed -> ph7]
//   ph5: A slot0-kh1 (tile 2i+2)   [dead after ph4]
//   ph6: B slot0-kh1 (tile 2i+2)
//   ph7: A slot1-kh0 (tile 2i+3)   [dead after ph6]
//   ph8: B slot1-kh0 (tile 2i+3) + vmcnt(4)  [guarantees ph3-6 landed ->
//                                              next ph1-4 reads]
// Last iter: ph3-8 staging skipped; ph4 uses vmcnt(0) (its ph1,2 stages are
// read at ph7,8 and nothing newer exists to leave in flight).
// Bank swizzle (64B rows, 4x16B units): phys_unit = logical ^ ((row>>1)&3);
// gload dest stays LINEAR, global SOURCE pre-swizzled (rule #21), ds_read
// uses swizzled offset. Verified involution (elem (5,13) round-trip).
// Accumulation stays k-ascending -> bit-identical absmax expected (race
// detector: any absmax drift = revert).
// ---------------------------------------------------------------------------
__global__ __launch_bounds__(512) void gemm_fused3(const uint16_t* __restrict__ A,
                                                   const uint16_t* __restrict__ W,
                                                   uint16_t* __restrict__ out0,
                                                   int K) {
  __shared__ uint16_t Al[2][2][8192];   // [slot][khalf][256*32]
  __shared__ uint16_t Bl[2][2][8192];
  const int tid = threadIdx.x;
  const int l = tid & 63, w = tid >> 6;
  const int wm = w >> 2, wn = w & 3;
  const int m0 = blockIdx.x * 256, n0 = blockIdx.y * 256;
  const int fr = l & 15;
  // swizzled read offset: logical unit u2=l>>4 at phys u2^((fr>>1)&3)
  const int pu = (((l >> 4) ^ ((fr >> 1) & 3)) * 8);
  // staging: lane covers row w*32+j*16+(l>>2), phys unit l&3; source col
  // pre-swizzled so phys holds logical (l&3)^((row>>1)&3) = (l&3)^((l>>3)&3)
  const int ssw = ((l & 3) ^ ((l >> 3) & 3)) * 8;
  const uint16_t* aS = A + (size_t)(m0 + w * 32 + (l >> 2)) * K + ssw;
  const uint16_t* wS = W + (size_t)(n0 + w * 32 + (l >> 2)) * K + ssw;

  f32x4 acc[8][4];
#pragma unroll
  for (int mi = 0; mi < 8; ++mi)
#pragma unroll
    for (int nj = 0; nj < 4; ++nj) {
      f32x4 z = {0.f, 0.f, 0.f, 0.f};
      acc[mi][nj] = z;
    }

#define STG_A(S, KH, KT) do {                                                \
    const uint16_t* _p = aS + (size_t)(KT) * 64 + (KH) * 32;                 \
    gload16(_p,                   &Al[S][KH][(w * 32) * 32]);                \
    gload16(_p + (size_t)16 * K,  &Al[S][KH][(w * 32 + 16) * 32]);           \
  } while (0)
#define STG_B(S, KH, KT) do {                                                \
    const uint16_t* _p = wS + (size_t)(KT) * 64 + (KH) * 32;                 \
    gload16(_p,                   &Bl[S][KH][(w * 32) * 32]);                \
    gload16(_p + (size_t)16 * K,  &Bl[S][KH][(w * 32 + 16) * 32]);           \
  } while (0)
#define LDA(S, KH, MI) (*(const s16x8*)&Al[S][KH][(wm * 128 + (MI) * 16 + fr) * 32 + pu])
#define LDB(S, KH, NJ) (*(const s16x8*)&Bl[S][KH][(wn * 64 + (NJ) * 16 + fr) * 32 + pu])
#define MFMA16(Q) do {                                                       \
    __builtin_amdgcn_s_setprio(1);                                           \
    _Pragma("unroll")                                                        \
    for (int mi = 0; mi < 8; ++mi)                                           \
      acc[mi][2*(Q)] = __builtin_amdgcn_mfma_f32_16x16x32_bf16(              \
          aF[mi], bF0, acc[mi][2*(Q)], 0, 0, 0);                             \
    _Pragma("unroll")                                                        \
    for (int mi = 0; mi < 8; ++mi)                                           \
      acc[mi][2*(Q)+1] = __builtin_amdgcn_mfma_f32_16x16x32_bf16(            \
          aF[mi], bF1, acc[mi][2*(Q)+1], 0, 0, 0);                           \
    __builtin_amdgcn_s_setprio(0);                                           \
  } while (0)

  // prologue: tile0 fully + tile1 kh0 (12 gloads), drain, publish
  STG_A(0, 0, 0); STG_B(0, 0, 0); STG_A(0, 1, 0); STG_B(0, 1, 0);
  STG_A(1, 0, 1); STG_B(1, 0, 1);
  VMCNT0();
  BARRIER();

  const int NI = K / 128;   // 2 K-tiles per iteration
  s16x8 aF[8], bF0, bF1;

  for (int i = 0; i < NI; ++i) {
    const bool nl = (i < NI - 1);
    const size_t t1 = 2 * i + 1, t2 = 2 * i + 2, t3 = 2 * i + 3;
    // ---- ph1: slot0 kh0, nj01 (A-read) ----
#pragma unroll
    for (int mi = 0; mi < 8; ++mi) aF[mi] = LDA(0, 0, mi);
    bF0 = LDB(0, 0, 0); bF1 = LDB(0, 0, 1);
    STG_A(1, 1, t1);
    BARRIER(); WAITLGKM(); MFMA16(0); BARRIER();
    // ---- ph2: slot0 kh0, nj23 ----
    bF0 = LDB(0, 0, 2); bF1 = LDB(0, 0, 3);
    STG_B(1, 1, t1);
    BARRIER(); WAITLGKM(); MFMA16(1); BARRIER();
    // ---- ph3: slot0 kh1, nj01 (A-read) ----
#pragma unroll
    for (int mi = 0; mi < 8; ++mi) aF[mi] = LDA(0, 1, mi);
    bF0 = LDB(0, 1, 0); bF1 = LDB(0, 1, 1);
    if (nl) STG_A(0, 0, t2);
    BARRIER(); WAITLGKM(); MFMA16(0); BARRIER();
    // ---- ph4: slot0 kh1, nj23 + checkpoint ----
    bF0 = LDB(0, 1, 2); bF1 = LDB(0, 1, 3);
    if (nl) STG_B(0, 0, t2);
    BARRIER(); WAITLGKM(); MFMA16(1);
    if (nl) VMCNT4(); else VMCNT0();
    BARRIER();
    // ---- ph5: slot1 kh0, nj01 (A-read) ----
#pragma unroll
    for (int mi = 0; mi < 8; ++mi) aF[mi] = LDA(1, 0, mi);
    bF0 = LDB(1, 0, 0); bF1 = LDB(1, 0, 1);
    if (nl) STG_A(0, 1, t2);
    BARRIER(); WAITLGKM(); MFMA16(0); BARRIER();
    // ---- ph6: slot1 kh0, nj23 ----
    bF0 = LDB(1, 0, 2); bF1 = LDB(1, 0, 3);
    if (nl) STG_B(0, 1, t2);
    BARRIER(); WAITLGKM(); MFMA16(1); BARRIER();
    // ---- ph7: slot1 kh1, nj01 (A-read) ----
#pragma unroll
    for (int mi = 0; mi < 8; ++mi) aF[mi] = LDA(1, 1, mi);
    bF0 = LDB(1, 1, 0); bF1 = LDB(1, 1, 1);
    if (nl) STG_A(1, 0, t3);
    BARRIER(); WAITLGKM(); MFMA16(0); BARRIER();
    // ---- ph8: slot1 kh1, nj23 + checkpoint ----
    bF0 = LDB(1, 1, 2); bF1 = LDB(1, 1, 3);
    if (nl) STG_B(1, 0, t3);
    BARRIER(); WAITLGKM(); MFMA16(1);
    VMCNT4();
    BARRIER();
  }
#undef STG_A
#undef STG_B
#undef LDA
#undef LDB
#undef MFMA16

  // block-uniform output region select (regions 32MB = 16777216 uint16 apart)
  uint16_t* Cb = out0 + (size_t)(n0 >> 11) * 16777216;
  const int r0 = m0 + wm * 128 + (l >> 4) * 4;
  const int c0 = (n0 & 2047) + wn * 64 + fr;
#pragma unroll
  for (int mi = 0; mi < 8; ++mi)
#pragma unroll
    for (int nj = 0; nj < 4; ++nj)
#pragma unroll
      for (int p = 0; p < 4; ++p) {
        const int row = r0 + mi * 16 + p;
        const int col = c0 + nj * 16;
        Cb[(size_t)row * 2048 + col] = f2b(acc[mi][nj][p]);
      }
}

// ---------------------------------------------------------------------------
// Final GEMM: C[M,N]fp32 = A @ W^T, 256x128 tile (round-11 version, unchanged
// this round for risk isolation; 8-phase port next if fused3 pays off).
// ---------------------------------------------------------------------------
__global__ __launch_bounds__(512, 2) void gemm_fin(const uint16_t* __restrict__ A,
                                                   const uint16_t* __restrict__ W,
                                                   float* __restrict__ C,
                                                   int Nd, int K) {
  __shared__ uint16_t As[3][256 * 32];
  __shared__ uint16_t Bs[3][128 * 32];
  const int tid = threadIdx.x;
  const int l = tid & 63, w = tid >> 6;
  const int wm = w >> 2, wn = w & 3;
  const int m0 = blockIdx.x * 256, n0 = blockIdx.y * 128;
  const int fr = l & 15, fk = (l >> 4) * 8;
  const int fkA = fk ^ ((fr & 3) << 3);
  const int sk = ((tid & 3) ^ ((tid >> 2) & 3)) * 8;
  const uint16_t* aP = A + (size_t)(m0 + w * 16 + (l >> 2)) * K + sk;
  const uint16_t* wP = W + (size_t)(n0 + w * 16 + (l >> 2)) * K + sk;

  f32x4 acc[8][2];
#pragma unroll
  for (int mi = 0; mi < 8; ++mi)
#pragma unroll
    for (int nj = 0; nj < 2; ++nj) {
      f32x4 z = {0.f, 0.f, 0.f, 0.f};
      acc[mi][nj] = z;
    }

#define STAGEF(T, BUF)                                                       \
  {                                                                          \
    const size_t k0_ = (size_t)(T) * 32;                                     \
    uint16_t* as_ = &As[BUF][w * 512];                                       \
    gload16(aP + k0_, as_);                                                  \
    gload16(aP + (size_t)128 * K + k0_, as_ + 4096);                         \
    gload16(wP + k0_, &Bs[BUF][w * 512]);                                    \
  }

  const int NT = K / 32;
  STAGEF(0, 0);
  STAGEF(1, 1);
  for (int t = 0; t < NT; ++t) {
    if (t < NT - 1) asm volatile("s_waitcnt vmcnt(3)" ::: "memory");
    else            asm volatile("s_waitcnt vmcnt(0)" ::: "memory");
    __builtin_amdgcn_s_barrier();
    __builtin_amdgcn_sched_barrier(0);
    if (t + 2 < NT) STAGEF(t + 2, (t + 2) % 3);
    const int cur = t % 3;
    s16x8 af[8], bf2[2];
    const uint16_t* Ab = &As[cur][(wm * 128 + fr) * 32 + fkA];
    const uint16_t* Bp = &Bs[cur][(wn * 32 + fr) * 32 + fkA];
#pragma unroll
    for (int mi = 0; mi < 8; ++mi) af[mi] = *(const s16x8*)(Ab + mi * 512);
#pragma unroll
    for (int nj = 0; nj < 2; ++nj) bf2[nj] = *(const s16x8*)(Bp + nj * 512);
    __builtin_amdgcn_s_setprio(1);
#pragma unroll
    for (int mi = 0; mi < 8; ++mi)
#pragma unroll
      for (int nj = 0; nj < 2; ++nj)
        acc[mi][nj] = __builtin_amdgcn_mfma_f32_16x16x32_bf16(af[mi], bf2[nj],
                                                              acc[mi][nj], 0, 0, 0);
    __builtin_amdgcn_s_setprio(0);
  }
#undef STAGEF

  const int r0 = m0 + wm * 128 + (l >> 4) * 4;
  const int c0 = n0 + wn * 32 + fr;
#pragma unroll
  for (int mi = 0; mi < 8; ++mi)
#pragma unroll
    for (int nj = 0; nj < 2; ++nj)
#pragma unroll
      for (int p = 0; p < 4; ++p)
        C[(size_t)(r0 + mi * 16 + p) * Nd + c0 + nj * 16] = acc[mi][nj][p];
}

// ---------------------------------------------------------------------------
// RoPE on fused bf16 qk rows (stride QKS) in place; q scaled by 1/16.
// ---------------------------------------------------------------------------
__global__ void rope_kernel(uint16_t* __restrict__ qk) {
  const int idx = blockIdx.x * 256 + threadIdx.x;   // < B*N*H*128
  const int i = idx & 127;
  const int h = (idx >> 7) & 3;
  const int n = (idx >> 9) & (Nn - 1);
  const int b = idx >> 21;
  const size_t base = ((size_t)(b * Nn + n)) * QKS + h * DK;
  const float invf = (float)exp((double)i * -0.071955784156063938);  // 1e4^(-i/128)
  const float theta = (float)n * invf;
  float sn, cs;
  sincosf(theta, &sn, &cs);
  float x1 = b2f(qk[base + i]), x2 = b2f(qk[base + 128 + i]);
  qk[base + i]       = f2b((x1 * cs - x2 * sn) * 0.0625f);
  qk[base + 128 + i] = f2b((x2 * cs + x1 * sn) * 0.0625f);
  x1 = b2f(qk[base + 1024 + i]); x2 = b2f(qk[base + 1024 + 128 + i]);
  qk[base + 1024 + i]       = f2b(x1 * cs - x2 * sn);
  qk[base + 1024 + 128 + i] = f2b(x2 * cs + x1 * sn);
}

// ---------------------------------------------------------------------------
// v transpose: vt[bh][w][n] = v[b][n][h*DV + w].  64x64 LDS tiles.
// ---------------------------------------------------------------------------
__global__ __launch_bounds__(256) void transpose_v(const uint16_t* __restrict__ v,
                                                   uint16_t* __restrict__ vt) {
  const int nt = blockIdx.x & 63;
  const int wt = (blockIdx.x >> 6) & 7;
  const int bh = blockIdx.x >> 9;
  const int b = bh >> 2, h = bh & 3;
  __shared__ uint16_t t[64][72];
  const int lr = threadIdx.x >> 2, lc = (threadIdx.x & 3) * 16;
  const uint16_t* src = v + ((size_t)(b * Nn + nt * 64 + lr)) * DM + h * DV + wt * 64 + lc;
  *(uint4*)&t[lr][lc]     = *(const uint4*)src;
  *(uint4*)&t[lr][lc + 8] = *(const uint4*)(src + 8);
  __syncthreads();
  uint16_t out[16];
#pragma unroll
  for (int e = 0; e < 16; ++e) out[e] = t[lc + e][lr];
  uint16_t* dst = vt + ((size_t)bh * 512 + wt * 64 + lr) * 4096 + nt * 64 + lc;
  *(uint4*)dst       = *(uint4*)&out[0];
  *(uint4*)(dst + 8) = *(uint4*)&out[8];
}

// ---------------------------------------------------------------------------
// k transpose + gamma-scale: kt[bh][d][n] = gamma_h^(63-(n&63)) * k[b][n][d]
// ---------------------------------------------------------------------------
__global__ __launch_bounds__(256) void transpose_k(const uint16_t* __restrict__ qk,
                                                   uint16_t* __restrict__ kt) {
  const int nt = blockIdx.x & 63;
  const int dt = (blockIdx.x >> 6) & 3;
  const int bh = blockIdx.x >> 8;
  const int b = bh >> 2, h = bh & 3;
  __shared__ uint16_t t[64][72];
  const int lr = threadIdx.x >> 2, lc = (threadIdx.x & 3) * 16;
  const uint16_t* src = qk + ((size_t)(b * Nn + nt * 64 + lr)) * QKS + 1024 + h * DK + dt * 64 + lc;
  *(uint4*)&t[lr][lc]     = *(const uint4*)src;
  *(uint4*)&t[lr][lc + 8] = *(const uint4*)(src + 8);
  __syncthreads();
  const float l2g = log2f(1.f - exp2f(-5.f - (float)h));
  uint16_t out[16];
#pragma unroll
  for (int e = 0; e < 16; ++e)
    out[e] = f2b(b2f(t[lc + e][lr]) * exp2f((float)(63 - (lc + e)) * l2g));
  uint16_t* dst = kt + ((size_t)bh * 256 + dt * 64 + lr) * 4096 + nt * 64 + lc;
  *(uint4*)dst       = *(uint4*)&out[0];
  *(uint4*)(dst + 8) = *(uint4*)&out[8];
}

// ---------------------------------------------------------------------------
// Intra-chunk attention via MFMA: attn[bh][c][i][j] (bf16).
// ---------------------------------------------------------------------------
__global__ __launch_bounds__(256) void attn_mfma(const uint16_t* __restrict__ qk,
                                                 uint16_t* __restrict__ attn) {
  const int c  = blockIdx.x & 63;
  const int bh = blockIdx.x >> 6;
  const int b = bh >> 2, h = bh & 3;
  const int tid = threadIdx.x;
  const int l = tid & 63, w = tid >> 6;
  const int fr = l & 15, fk = (l >> 4) * 8;
  const int n0 = c * CH;
  const uint16_t* qbase = qk + ((size_t)(b * Nn + n0)) * QKS + h * DK;
  const uint16_t* kbase = qbase + 1024;
  f32x4 acc[4];
#pragma unroll
  for (int nj = 0; nj < 4; ++nj) {
    f32x4 z = {0.f, 0.f, 0.f, 0.f};
    acc[nj] = z;
  }
#pragma unroll
  for (int ks = 0; ks < 8; ++ks) {
    s16x8 qf = *(const s16x8*)(qbase + (size_t)(w * 16 + fr) * QKS + ks * 32 + fk);
    s16x8 kf[4];
#pragma unroll
    for (int nj = 0; nj < 4; ++nj)
      kf[nj] = *(const s16x8*)(kbase + (size_t)(nj * 16 + fr) * QKS + ks * 32 + fk);
#pragma unroll
    for (int nj = 0; nj < 4; ++nj)
      acc[nj] = __builtin_amdgcn_mfma_f32_16x16x32_bf16(qf, kf[nj], acc[nj], 0, 0, 0);
  }
  const float l2g = log2f(1.f - exp2f(-5.f - (float)h));
  uint16_t* ab = attn + ((size_t)bh * 64 + c) * 4096;
  const int rbase = (l >> 4) * 4;
#pragma unroll
  for (int pp = 0; pp < 4; ++pp) {
    const int i = w * 16 + rbase + pp;
#pragma unroll
    for (int nj = 0; nj < 4; ++nj) {
      const int j = nj * 16 + fr;
      const float val = (i >= j) ? acc[nj][pp] * exp2f((float)(i - j) * l2g) : 0.f;
      ab[(size_t)i * 64 + j] = f2b(val);
    }
  }
}

// ---------------------------------------------------------------------------
// Kernel A: U_c^T[w,d] = sum_j vt[w,j] * kt[d,j]  (direct-global fragments)
// ---------------------------------------------------------------------------
__global__ __launch_bounds__(256) void chunk_outer(const uint16_t* __restrict__ kt,
                                                   const uint16_t* __restrict__ vt,
                                                   uint16_t* __restrict__ U, int p) {
  const int c  = blockIdx.x & 63;
  const int bh = blockIdx.x >> 6;
  const int tid = threadIdx.x;
  const int l = tid & 63, w = tid >> 6;
  const int wrow = (w >> 1) * 64;     // w' base (M)
  const int wcol = (w & 1) * 128;     // d  base (N)
  const int fr = l & 15, fk = (l >> 4) * 8;
  const int n0 = c * CH;
  const uint16_t* vtb = vt + ((size_t)bh * 512 + p * 128) * 4096 + n0;
  const uint16_t* ktb = kt + ((size_t)bh * 256) * 4096 + n0;
  f32x4 acc[4][8];
#pragma unroll
  for (int mi = 0; mi < 4; ++mi)
#pragma unroll
    for (int nj = 0; nj < 8; ++nj) {
      f32x4 z = {0.f, 0.f, 0.f, 0.f};
      acc[mi][nj] = z;
    }
#pragma unroll
  for (int ks = 0; ks < 2; ++ks) {
    s16x8 af[4], bf8[8];
#pragma unroll
    for (int mi = 0; mi < 4; ++mi)
      af[mi] = *(const s16x8*)(vtb + (size_t)(wrow + mi * 16 + fr) * 4096 + ks * 32 + fk);
#pragma unroll
    for (int nj = 0; nj < 8; ++nj)
      bf8[nj] = *(const s16x8*)(ktb + (size_t)(wcol + nj * 16 + fr) * 4096 + ks * 32 + fk);
#pragma unroll
    for (int mi = 0; mi < 4; ++mi)
#pragma unroll
      for (int nj = 0; nj < 8; ++nj)
        acc[mi][nj] = __builtin_amdgcn_mfma_f32_16x16x32_bf16(af[mi], bf8[nj],
                                                              acc[mi][nj], 0, 0, 0);
  }
  uint16_t* Ub = U + (size_t)bh * 2097152 + (size_t)c * 32768;
  const int rbase = (l >> 4) * 4;
#pragma unroll
  for (int mi = 0; mi < 4; ++mi)
#pragma unroll
    for (int nj = 0; nj < 8; ++nj)
#pragma unroll
      for (int pp = 0; pp < 4; ++pp) {
        const int wq = wrow + mi * 16 + rbase + pp;
        const int d  = wcol + nj * 16 + fr;
        Ub[(size_t)wq * 256 + d] = f2b(acc[mi][nj][pp]);
      }
}

// ---------------------------------------------------------------------------
// Kernel B: in-place state scan (slot c -> S_c), 8-batch load prefetch.
// ---------------------------------------------------------------------------
__global__ __launch_bounds__(256) void state_scan(uint16_t* __restrict__ U) {
  const int gid = blockIdx.x * 256 + threadIdx.x;   // < 8*32768 = 262144
  const int bh = gid >> 15;
  const int e  = gid & 32767;
  const int h  = bh & 3;
  const float l2g = log2f(1.f - exp2f(-5.f - (float)h));
  const float gC = exp2f(64.f * l2g);
  uint16_t* p = U + (size_t)bh * 2097152 + e;
  float S = 0.f;
  for (int cb = 0; cb < 8; ++cb) {
    uint16_t* base = p + (size_t)cb * 8 * 32768;
    float u[8];
#pragma unroll
    for (int ee = 0; ee < 8; ++ee) u[ee] = b2f(base[(size_t)ee * 32768]);
#pragma unroll
    for (int ee = 0; ee < 8; ++ee) {
      base[(size_t)ee * 32768] = f2b(S);
      S = gC * S + u[ee];
    }
  }
}

// ---------------------------------------------------------------------------
// Kernel C: o[i,w] = (attn_c @ v_c)[i,w] + gamma^(i+1)*(q_c @ S_c)[i,w]
// ---------------------------------------------------------------------------
__global__ __launch_bounds__(256) void scan_out(const uint16_t* __restrict__ qk,
                                                const uint16_t* __restrict__ vt,
                                                const uint16_t* __restrict__ attn,
                                                const uint16_t* __restrict__ U,
                                                uint16_t* __restrict__ o, int p) {
  const int c  = blockIdx.x & 63;
  const int bh = blockIdx.x >> 6;
  const int b = bh >> 2, h = bh & 3;
  const int tid = threadIdx.x;
  const int l = tid & 63, wv = tid >> 6;
  const int wcol = wv * 32;                 // output col base (within pass 128)
  const int fr = l & 15, fk = (l >> 4) * 8;
  const int n0 = c * CH;
  f32x4 aQS[4][2], aPV[4][2];
#pragma unroll
  for (int mi = 0; mi < 4; ++mi)
#pragma unroll
    for (int nj = 0; nj < 2; ++nj) {
      f32x4 z = {0.f, 0.f, 0.f, 0.f};
      aQS[mi][nj] = z; aPV[mi][nj] = z;
    }
  const uint16_t* qbase = qk + ((size_t)(b * Nn + n0)) * QKS + h * DK;
  const uint16_t* Ub = U + (size_t)bh * 2097152 + (size_t)c * 32768;
  // q @ S  (K = 256)
#pragma unroll
  for (int ks = 0; ks < 8; ++ks) {
    s16x8 qf[4], sf[2];
#pragma unroll
    for (int mi = 0; mi < 4; ++mi)
      qf[mi] = *(const s16x8*)(qbase + (size_t)(mi * 16 + fr) * QKS + ks * 32 + fk);
#pragma unroll
    for (int nj = 0; nj < 2; ++nj)
      sf[nj] = *(const s16x8*)(Ub + (size_t)(wcol + nj * 16 + fr) * 256 + ks * 32 + fk);
#pragma unroll
    for (int mi = 0; mi < 4; ++mi)
#pragma unroll
      for (int nj = 0; nj < 2; ++nj)
        aQS[mi][nj] = __builtin_amdgcn_mfma_f32_16x16x32_bf16(qf[mi], sf[nj],
                                                              aQS[mi][nj], 0, 0, 0);
  }
  // attn @ v  (K = 64)
  const uint16_t* ab = attn + ((size_t)bh * 64 + c) * 4096;
  const uint16_t* vtb = vt + ((size_t)bh * 512 + p * 128) * 4096 + n0;
#pragma unroll
  for (int ks = 0; ks < 2; ++ks) {
    s16x8 af[4], vf[2];
#pragma unroll
    for (int mi = 0; mi < 4; ++mi)
      af[mi] = *(const s16x8*)(ab + (size_t)(mi * 16 + fr) * 64 + ks * 32 + fk);
#pragma unroll
    for (int nj = 0; nj < 2; ++nj)
      vf[nj] = *(const s16x8*)(vtb + (size_t)(wcol + nj * 16 + fr) * 4096 + ks * 32 + fk);
#pragma unroll
    for (int mi = 0; mi < 4; ++mi)
#pragma unroll
      for (int nj = 0; nj < 2; ++nj)
        aPV[mi][nj] = __builtin_amdgcn_mfma_f32_16x16x32_bf16(af[mi], vf[nj],
                                                              aPV[mi][nj], 0, 0, 0);
  }
  const float l2g = log2f(1.f - exp2f(-5.f - (float)h));
  const int rbase = (l >> 4) * 4;
#pragma unroll
  for (int mi = 0; mi < 4; ++mi)
#pragma unroll
    for (int pp = 0; pp < 4; ++pp) {
      const int i = mi * 16 + rbase + pp;
      const float gi = exp2f((float)(i + 1) * l2g);
#pragma unroll
      for (int nj = 0; nj < 2; ++nj) {
        const int wc_ = wcol + nj * 16 + fr;
        const float val = aPV[mi][nj][pp] + gi * aQS[mi][nj][pp];
        o[((size_t)(b * Nn + n0 + i)) * DM + h * DV + p * 128 + wc_] = f2b(val);
      }
    }
}

// ---------------------------------------------------------------------------
// GroupNorm over DV per (b,n,h) + SiLU gate (o bf16), in place into g.
// ---------------------------------------------------------------------------
__global__ __launch_bounds__(256) void gn_gate(const uint16_t* __restrict__ o,
                                               uint16_t* __restrict__ g,
                                               const float* __restrict__ gw) {
  const int bn = blockIdx.x;
  const int tid = threadIdx.x;
  const int h = tid >> 6;
  const int lane = tid & 63;
  const size_t base = (size_t)bn * DM + h * DV + lane * 8;
  uint4 ov4 = *(const uint4*)&o[base];
  float ov[8] = { b2f((uint16_t)ov4.x), b2f((uint16_t)(ov4.x >> 16)),
                  b2f((uint16_t)ov4.y), b2f((uint16_t)(ov4.y >> 16)),
                  b2f((uint16_t)ov4.z), b2f((uint16_t)(ov4.z >> 16)),
                  b2f((uint16_t)ov4.w), b2f((uint16_t)(ov4.w >> 16)) };
  float ss = 0.f;
#pragma unroll
  for (int e = 0; e < 8; ++e) ss += ov[e] * ov[e];
#pragma unroll
  for (int m = 1; m < 64; m <<= 1) ss += __shfl_xor(ss, m, 64);
  const float r = rsqrtf(ss * (1.f / 512.f) + 1e-5f);
  uint4 gv = *(const uint4*)&g[base];
  float gf[8] = { b2f((uint16_t)gv.x), b2f((uint16_t)(gv.x >> 16)),
                  b2f((uint16_t)gv.y), b2f((uint16_t)(gv.y >> 16)),
                  b2f((uint16_t)gv.z), b2f((uint16_t)(gv.z >> 16)),
                  b2f((uint16_t)gv.w), b2f((uint16_t)(gv.w >> 16)) };
  const float* gwp = gw + lane * 8;
  uint16_t res[8];
#pragma unroll
  for (int e = 0; e < 8; ++e) {
    float sil = gf[e] / (1.f + expf(-gf[e]));
    res[e] = f2b(ov[e] * r * gwp[e] * sil);
  }
  uint4 outv;
  outv.x = (uint32_t)res[0] | ((uint32_t)res[1] << 16);
  outv.y = (uint32_t)res[2] | ((uint32_t)res[3] << 16);
  outv.z = (uint32_t)res[4] | ((uint32_t)res[5] << 16);
  outv.w = (uint32_t)res[6] | ((uint32_t)res[7] << 16);
  *(uint4*)&g[base] = outv;
}

// ---------------------------------------------------------------------------
// ws layout (MB), peak 160 (proven size). Overlays, write-before-read ordered:
//   [  0, 32)  xb (dead after fused GEMM)            -> U (scan)
//   [ 32, 64)  qkb   [ 64, 96) vb -> kt[64,80) attn[80,84) wob[84,92)
//   [ 96,128)  gb
//   [128,152)  wall (stacked Wq;Wk;Wv;Wg, dead after fused GEMM)
//                                                    -> vt[128,160)
// o16 (bf16) lives in d_out's first 32MB until gn_gate; final GEMM overwrites
// d_out fp32. Every region fully written before read -> graph-replay safe.
// ---------------------------------------------------------------------------
extern "C" void kernel_launch(void* const* d_in, const int* in_sizes, int n_in,
                              void* d_out, int out_size, void* d_ws, size_t ws_size,
                              hipStream_t stream) {
  const float* x  = (const float*)d_in[0];
  const float* Wq = (const float*)d_in[1];
  const float* Wk = (const float*)d_in[2];
  const float* Wv = (const float*)d_in[3];
  const float* Wg = (const float*)d_in[4];
  const float* Wo = (const float*)d_in[5];
  const float* gw = (const float*)d_in[6];

  char* base = (char*)d_ws;
  uint16_t* xb   = (uint16_t*)(base);                       // [0,32)
  uint16_t* U    = (uint16_t*)(base);                       // overlays xb (scan)
  uint16_t* qkb  = (uint16_t*)(base + ((size_t)32 << 20));  // [32,64)
  uint16_t* vb   = (uint16_t*)(base + ((size_t)64 << 20));  // [64,96)
  uint16_t* kt   = (uint16_t*)(base + ((size_t)64 << 20));  // overlays vb
  uint16_t* attn = (uint16_t*)(base + ((size_t)80 << 20));  // overlays vb
  uint16_t* wob  = (uint16_t*)(base + ((size_t)84 << 20));  // overlays vb
  uint16_t* gb   = (uint16_t*)(base + ((size_t)96 << 20));  // [96,128)
  uint16_t* wall = (uint16_t*)(base + ((size_t)128 << 20)); // [128,152)
  uint16_t* vt   = (uint16_t*)(base + ((size_t)128 << 20)); // overlays wall
  uint16_t* qb   = qkb;                    // q = cols 0-1023
  uint16_t* o16  = (uint16_t*)d_out;       // bf16 o scratch (first 32MB)

  dim3 blk(256), blkG(512);
  // phase 1: conversions + ONE fused GEMM (qk|v|g), 768 blocks
  conv_f2b<<<dim3(8192), blk, 0, stream>>>(x, xb, M * DM / 8);
  conv_w4<<<dim3(6144), blk, 0, stream>>>(Wq, Wk, Wv, Wg, wall);
  gemm_fused3<<<dim3(M/256, 6144/256), blkG, 0, stream>>>(xb, wall, qkb, DM);
  // phase 2: rope; transposes (vb, wall die); attn
  rope_kernel<<<dim3((Bb*Nn*Hh*128)/256), blk, 0, stream>>>(qkb);
  transpose_v<<<dim3(8*8*64), blk, 0, stream>>>(vb, vt);     // vb -> dead
  conv_f2b<<<dim3(2048), blk, 0, stream>>>(Wo, wob, DM * DM / 8);
  transpose_k<<<dim3(8*4*64), blk, 0, stream>>>(qkb, kt);
  attn_mfma<<<dim3(Bb*Hh*NC), blk, 0, stream>>>(qkb, attn);
  // scan: 4 passes of 128 dv cols; U overlays dead xb
  for (int p = 0; p < 4; ++p) {
    chunk_outer<<<dim3(Bb*Hh*NC),  blk, 0, stream>>>(kt, vt, U, p);
    state_scan<<<dim3(1024),       blk, 0, stream>>>(U);
    scan_out<<<dim3(Bb*Hh*NC),     blk, 0, stream>>>(qb, vt, attn, U, o16, p);
  }
  // epilogue
  gn_gate<<<dim3(M), blk, 0, stream>>>(o16, gb, gw);
  gemm_fin<<<dim3(M/256, DM/128), blkG, 0, stream>>>(gb, wob, (float*)d_out, DM, DM);
}